// Round 7
// baseline (258.849 us; speedup 1.0000x reference)
//
#include <hip/hip_runtime.h>
#include <hip/hip_bf16.h>

#define LL 4096
#define DM 96
#define DI 192
#define NS 16
#define RK 6
#define RKP 8              // padded stride for dt coeffs (16B alignment)
#define KD 4
#define CPROJ 38
#define NCH (KD*DI)        // 768 (k,d) pairs
#define NC (KD*DI*NS)      // 12288 independent chains
#define PT 32              // t-tile for proj == scan chunk (CHB=7)
#define WS 196             // LDS row stride (4*odd -> quad-bank spread)
#define OT 8               // l-tile for k_out
#define CHB 7
#define CHN (1<<CHB)       // 128 chunks
#define CS (LL>>CHB)       // 32 steps per chunk == PT
#define L2E 1.44269504f

__device__ __forceinline__ float bf2f(unsigned short u){
  unsigned int x = ((unsigned int)u) << 16;
  return __uint_as_float(x);
}
__device__ __forceinline__ float b2f(__hip_bfloat16 v){ return __bfloat162float(v); }

// inline dtype detect: 64 lanes sample even halfwords of x
__device__ __forceinline__ void detect_bf16(const unsigned short* __restrict__ xh, int tid, int* sflag){
  if (tid < 64){
    unsigned short u = xh[2*tid];
    int e = (u >> 7) & 0xFF;
    int sane = (e >= 107 && e <= 131) ? 1 : 0;
    unsigned long long m = __ballot(sane);
    if (tid == 0) *sflag = (__popcll(m) >= 32) ? 1 : 0;
  }
}

__device__ __forceinline__ int dir_map(int k, int t){
  if (k==0) return t;
  if (k==1) return ((t&63)<<6) | (t>>6);
  if (k==2) return 4095 - t;
  int u = 4095 - t; return ((u&63)<<6) | (u>>6);
}

struct P12 { const void* p[12]; };

// -------- K1: merged {in_proj GEMM (raw w, raw x)} + {param convert 2..11} --------
__global__ void __launch_bounds__(384) k_inprojcvt(P12 ptrs, float* __restrict__ cvt,
                         float* __restrict__ xx, float* __restrict__ z) {
  __shared__ float xr[8*DM];
  __shared__ int sflag;
  int tid = threadIdx.x; // 384
  detect_bf16((const unsigned short*)ptrs.p[0], tid, &sflag);
  __syncthreads();
  int f = sflag;
  if (blockIdx.x >= LL/8){
    const int off[12] = {0,36864,38592,38784,67968,72576,73344,85632,86400,86592,86784,105216};
    int i = (blockIdx.x - LL/8)*384 + tid + 36864;
    if (i < 105216){
      int j = 1;
      #pragma unroll
      for (int s = 2; s < 11; s++) if (i >= off[s]) j = s;
      int e = i - off[j];
      const void* src = ptrs.p[j+1];
      cvt[i] = f ? b2f(((const __hip_bfloat16*)src)[e]) : ((const float*)src)[e];
    }
    return;
  }
  int l0 = blockIdx.x * 8;
  if (f){
    const __hip_bfloat16* xb = (const __hip_bfloat16*)ptrs.p[0] + (size_t)l0*DM;
    for (int i = tid; i < 8*DM; i += 384) xr[i] = b2f(xb[i]);
  } else {
    const float* xf = (const float*)ptrs.p[0] + (size_t)l0*DM;
    for (int i = tid; i < 8*DM; i += 384) xr[i] = xf[i];
  }
  __syncthreads();
  int e = tid;
  float acc[8];
  #pragma unroll
  for (int i=0;i<8;i++) acc[i]=0.f;
  const float4* xr4 = (const float4*)xr;   // rows of 24 float4
  if (f){
    const ushort4* wb = (const ushort4*)((const unsigned short*)ptrs.p[1] + (size_t)e*DM);
    #pragma unroll 4
    for (int c4=0;c4<DM/4;c4++){
      ushort4 uv = wb[c4];
      float4 wv = make_float4(bf2f(uv.x), bf2f(uv.y), bf2f(uv.z), bf2f(uv.w));
      #pragma unroll
      for (int i=0;i<8;i++){
        float4 xv = xr4[i*24 + c4];
        acc[i] = fmaf(wv.x,xv.x,fmaf(wv.y,xv.y,fmaf(wv.z,xv.z,fmaf(wv.w,xv.w,acc[i]))));
      }
    }
  } else {
    const float4* wr4 = (const float4*)((const float*)ptrs.p[1] + (size_t)e*DM);
    #pragma unroll 4
    for (int c4=0;c4<DM/4;c4++){
      float4 wv = wr4[c4];
      #pragma unroll
      for (int i=0;i<8;i++){
        float4 xv = xr4[i*24 + c4];
        acc[i] = fmaf(wv.x,xv.x,fmaf(wv.y,xv.y,fmaf(wv.z,xv.z,fmaf(wv.w,xv.w,acc[i]))));
      }
    }
  }
  if (e < DI) {
    #pragma unroll
    for (int i=0;i<8;i++) xx[(l0+i)*DI + e] = acc[i];
  } else {
    int e2 = e - DI;
    #pragma unroll
    for (int i=0;i<8;i++) z[(l0+i)*DI + e2] = acc[i];
  }
}

// -------- K2: depthwise 3x3 conv + bias + SiLU --------
__global__ void k_conv(const float* __restrict__ xx,
                       const float* __restrict__ cw,
                       const float* __restrict__ cb,
                       float* __restrict__ xc) {
  int l = blockIdx.x;
  int d = threadIdx.x; // 192
  int h = l >> 6, w = l & 63;
  float acc = cb[d];
  #pragma unroll
  for (int ki=0; ki<3; ki++){
    int hh = h + ki - 1;
    if ((unsigned)hh >= 64u) continue;
    #pragma unroll
    for (int kj=0;kj<3;kj++){
      int wj = w + kj - 1;
      if ((unsigned)wj >= 64u) continue;
      acc = fmaf(cw[d*9 + ki*3 + kj], xx[(hh*64+wj)*DI + d], acc);
    }
  }
  xc[l*DI + d] = acc / (1.f + __expf(-acc));
}

// -------- K3/K5: fused {proj -> LDS} + {scan}, 384 threads.
// Scan: thread=(d=tid%192, half=tid/192); each half owns 8 n-chains
// (halves are wave-aligned: 192 = 3 waves). 12 active waves/CU during scan
// (was 6) -> 2x latency hiding; per-thread exp2 count halves.
// MODE 0: summaries (skips C-rows of proj; Cs never read).
// MODE 1: final pass; y = half0 partial + half1 partial via LDS (4 groups of
// 8 steps, one barrier per group; partials in registers, static indexing). --------
template<int MODE>
__global__ void __launch_bounds__(384, 3) k_projscan(
                      const float* __restrict__ xc,
                      const float* __restrict__ xpw,
                      const float* __restrict__ A_logs,
                      const float* __restrict__ dtw,
                      const float* __restrict__ dtb,
                      float* __restrict__ cumDbuf,
                      float* __restrict__ Harr,
                      float* __restrict__ ydir) {
  __shared__ float wl[CPROJ*WS];   // 29.8 KB (reused as ybuf in MODE1 scan)
  __shared__ float xs[PT*WS];      // 25.1 KB
  __shared__ float ds_[PT*RKP];    // 1 KB
  __shared__ float Bs[PT*NS];      // 2 KB
  __shared__ float Cs[PT*NS];      // 2 KB   (total ~59 KB -> 2 blocks/CU)
  int b = blockIdx.x;              // KD * 128
  int k = b >> 7;
  int c = b & 127;
  int t_base = c * PT;             // == t0 of chunk c (CS == PT)
  int tid = threadIdx.x;           // 384

  // ---- proj staging ----
  for (int idx = tid; idx < CPROJ*DI; idx += 384){
    int cc = idx / DI, j = idx - cc*DI;
    wl[cc*WS + j] = xpw[(k*CPROJ + cc)*DI + j];
  }
  for (int idx = tid; idx < PT*DI; idx += 384){
    int tt = idx / DI, j = idx - tt*DI;
    xs[tt*WS + j] = xc[(size_t)dir_map(k, t_base + tt)*DI + j];
  }
  __syncthreads();

  // ---- proj compute -> LDS ds_/Bs/Cs (256 threads; MODE0 skips C rows) ----
  if (tid < 256){
    int tg = tid & 7;        // t cols {tg, tg+8, tg+16, tg+24}
    int ty = tid >> 3;       // rows {ty, ty+32 if <38}
    int cc0 = ty;
    int need0 = (MODE == 0) ? (cc0 < RK+NS) : 1;       // MODE0: skip C rows
    int has2 = (MODE == 0) ? 0 : (ty + 32 < CPROJ);    // rows 32..37 are all C
    int cc1 = has2 ? (ty + 32) : ty;
    float a0x=0.f,a0y=0.f,a0z=0.f,a0w=0.f;
    float a1x=0.f,a1y=0.f,a1z=0.f,a1w=0.f;
    const float4* w0p = (const float4*)&wl[cc0*WS];
    const float4* w1p = (const float4*)&wl[cc1*WS];
    const float4* x0p = (const float4*)&xs[(tg     )*WS];
    const float4* x1p = (const float4*)&xs[(tg +  8)*WS];
    const float4* x2p = (const float4*)&xs[(tg + 16)*WS];
    const float4* x3p = (const float4*)&xs[(tg + 24)*WS];
    if (need0){
      #pragma unroll 4
      for (int jc = 0; jc < DI/4; jc++){
        float4 w0 = w0p[jc], w1 = w1p[jc];
        float4 x0 = x0p[jc], x1 = x1p[jc], x2 = x2p[jc], x3 = x3p[jc];
        a0x = fmaf(w0.x,x0.x,fmaf(w0.y,x0.y,fmaf(w0.z,x0.z,fmaf(w0.w,x0.w,a0x))));
        a0y = fmaf(w0.x,x1.x,fmaf(w0.y,x1.y,fmaf(w0.z,x1.z,fmaf(w0.w,x1.w,a0y))));
        a0z = fmaf(w0.x,x2.x,fmaf(w0.y,x2.y,fmaf(w0.z,x2.z,fmaf(w0.w,x2.w,a0z))));
        a0w = fmaf(w0.x,x3.x,fmaf(w0.y,x3.y,fmaf(w0.z,x3.z,fmaf(w0.w,x3.w,a0w))));
        if (has2){
          a1x = fmaf(w1.x,x0.x,fmaf(w1.y,x0.y,fmaf(w1.z,x0.z,fmaf(w1.w,x0.w,a1x))));
          a1y = fmaf(w1.x,x1.x,fmaf(w1.y,x1.y,fmaf(w1.z,x1.z,fmaf(w1.w,x1.w,a1y))));
          a1z = fmaf(w1.x,x2.x,fmaf(w1.y,x2.y,fmaf(w1.z,x2.z,fmaf(w1.w,x2.w,a1z))));
          a1w = fmaf(w1.x,x3.x,fmaf(w1.y,x3.y,fmaf(w1.z,x3.z,fmaf(w1.w,x3.w,a1w))));
        }
      }
    }
    float accs0[4] = {a0x,a0y,a0z,a0w};
    float accs1[4] = {a1x,a1y,a1z,a1w};
    #pragma unroll
    for (int i=0;i<4;i++){
      int t = tg + 8*i;            // LOCAL chunk index 0..31
      if (need0){
        int cc = cc0; float v = accs0[i];
        if (cc < RK)            ds_[t*RKP + cc] = v;
        else if (cc < RK+NS)    Bs [t*NS + (cc-RK)] = v;
        else                    Cs [t*NS + (cc-RK-NS)] = v;
      }
      if (has2){
        int cc = cc1; float v = accs1[i];
        if (cc < RK+NS)         Bs [t*NS + (cc-RK)] = v;
        else                    Cs [t*NS + (cc-RK-NS)] = v;
      }
    }
  }
  __syncthreads();

  // ---- scan over the LDS-resident chunk: all 384 threads ----
  {
    int half = (tid >= DI) ? 1 : 0;      // wave-aligned (192 = 3 waves)
    int d = tid - half*DI;
    int kd = k*DI + d;
    int n0 = half*8;
    float bt = dtb[kd];
    float w0 = dtw[kd*RK+0], w1 = dtw[kd*RK+1], w2 = dtw[kd*RK+2];
    float w3 = dtw[kd*RK+3], w4 = dtw[kd*RK+4], w5 = dtw[kd*RK+5];
    float A2[8], h[8];
    {
      const float4* ap = (const float4*)&A_logs[kd*NS] + half*2;
      float4 a0 = ap[0], a1 = ap[1];
      A2[0] = -__expf(a0.x)*L2E; A2[1] = -__expf(a0.y)*L2E;
      A2[2] = -__expf(a0.z)*L2E; A2[3] = -__expf(a0.w)*L2E;
      A2[4] = -__expf(a1.x)*L2E; A2[5] = -__expf(a1.y)*L2E;
      A2[6] = -__expf(a1.z)*L2E; A2[7] = -__expf(a1.w)*L2E;
    }
    if (MODE == 0){
      #pragma unroll
      for (int n=0;n<8;n++) h[n] = 0.f;
    } else {
      const float4* hp = (const float4*)(Harr + ((size_t)c*NCH + kd)*16) + half*2;
      float4 h0 = hp[0], h1 = hp[1];
      h[0]=h0.x; h[1]=h0.y; h[2]=h0.z; h[3]=h0.w;
      h[4]=h1.x; h[5]=h1.y; h[6]=h1.z; h[7]=h1.w;
    }
    float cumD = 0.f;
    float* ybuf = wl;                    // proj weights dead after barrier
    #pragma unroll
    for (int g=0; g<4; g++){
      float yp[8];
      #pragma unroll
      for (int si=0; si<8; si++){
        int s = g*8 + si;
        float4 lo = *(const float4*)(ds_ + s*RKP);
        float4 hi = *(const float4*)(ds_ + s*RKP + 4);
        float v = bt;
        v = fmaf(w0, lo.x, v); v = fmaf(w1, lo.y, v); v = fmaf(w2, lo.z, v);
        v = fmaf(w3, lo.w, v); v = fmaf(w4, hi.x, v); v = fmaf(w5, hi.y, v);
        float sp = (v > 20.f) ? v : __logf(1.f + __expf(v));
        if (MODE == 0) cumD += sp;
        float sx = sp * xs[s*WS + d];
        float4 b0 = *(const float4*)(Bs + s*NS + n0);
        float4 b1 = *(const float4*)(Bs + s*NS + n0 + 4);
        float bb[8] = {b0.x,b0.y,b0.z,b0.w, b1.x,b1.y,b1.z,b1.w};
        #pragma unroll
        for (int n=0;n<8;n++){
          float aa = exp2f(sp*A2[n]);
          h[n] = fmaf(aa, h[n], sx*bb[n]);
        }
        if (MODE == 1){
          float4 c0 = *(const float4*)(Cs + s*NS + n0);
          float4 c1 = *(const float4*)(Cs + s*NS + n0 + 4);
          float cc4[8] = {c0.x,c0.y,c0.z,c0.w, c1.x,c1.y,c1.z,c1.w};
          float y0 = fmaf(h[4], cc4[4], h[0]*cc4[0]);
          float y1 = fmaf(h[5], cc4[5], h[1]*cc4[1]);
          float y2 = fmaf(h[6], cc4[6], h[2]*cc4[2]);
          float y3 = fmaf(h[7], cc4[7], h[3]*cc4[3]);
          yp[si] = (y0+y1)+(y2+y3);
        }
      }
      if (MODE == 1){
        if (half == 1){
          #pragma unroll
          for (int si=0; si<8; si++) ybuf[(g*8+si)*WS + d] = yp[si];
        }
        __syncthreads();
        if (half == 0){
          #pragma unroll
          for (int si=0; si<8; si++){
            int s = g*8 + si;
            int row = dir_map(k, t_base + s);
            ydir[((size_t)k*LL + row)*DI + d] = yp[si] + ybuf[s*WS + d];
          }
        }
      }
    }
    if (MODE == 0){
      if (half == 0) cumDbuf[(size_t)c*NCH + kd] = cumD;
      float4* hp = (float4*)(Harr + ((size_t)c*NCH + kd)*16) + half*2;
      hp[0] = make_float4(h[0],h[1],h[2],h[3]);
      hp[1] = make_float4(h[4],h[5],h[6],h[7]);
    }
  }
}

// -------- K4: cross-chunk combine, LDS-staged (CHB=7) --------
template<int CB>
__global__ void __launch_bounds__(512) k_scan2(const float* __restrict__ A_logs,
                                               const float* __restrict__ cumDbuf,
                                               float* __restrict__ Harr) {
  constexpr int CH = 1 << CB;
  constexpr int CHP = CH + 1;      // +1 pad
  __shared__ float hs[64][CHP];    // 33 KB @CB=7
  __shared__ float cds[4][CH];
  int tid = threadIdx.x;           // 512
  int base = blockIdx.x * 64;      // chain base
  int kd0 = blockIdx.x * 4;
  for (int i4 = tid; i4 < 16*CH; i4 += 512){
    int c = i4 >> 4;
    int jv = (i4 & 15) * 4;
    float4 v = *(const float4*)&Harr[(size_t)c*NC + base + jv];
    hs[jv][c] = v.x; hs[jv+1][c] = v.y; hs[jv+2][c] = v.z; hs[jv+3][c] = v.w;
  }
  for (int i = tid; i < 4*CH; i += 512){
    int c = i >> 2, kdl = i & 3;
    cds[kdl][c] = cumDbuf[(size_t)c*NCH + kd0 + kdl];
  }
  __syncthreads();
  if (tid < 64){
    float A2 = -__expf(A_logs[base + tid]) * L2E;
    const float* cd = cds[tid >> 4];
    float* hr = hs[tid];
    float h = 0.f;
    #pragma unroll 4
    for (int c = 0; c < CH; c++){
      float hl = hr[c];
      float P = exp2f(A2 * cd[c]);
      hr[c] = h;                   // entry state
      h = fmaf(P, h, hl);
    }
  }
  __syncthreads();
  for (int i4 = tid; i4 < 16*CH; i4 += 512){
    int c = i4 >> 4;
    int jv = (i4 & 15) * 4;
    float4 v = make_float4(hs[jv][c], hs[jv+1][c], hs[jv+2][c], hs[jv+3][c]);
    *(float4*)&Harr[(size_t)c*NC + base + jv] = v;
  }
}

// -------- K6: fused gather + LayerNorm + gate + out_proj --------
__global__ void __launch_bounds__(192) k_out(
                      const float* __restrict__ ydir,
                      const float* __restrict__ xc,
                      const float* __restrict__ z,
                      const float* __restrict__ Ds,
                      const float* __restrict__ ln_g,
                      const float* __restrict__ ln_b,
                      const float* __restrict__ opw,
                      void* __restrict__ out,
                      const unsigned short* __restrict__ xh) {
  __shared__ float gs[OT*WS];      // 6.3 KB
  __shared__ float ps[2][OT][24];
  __shared__ float mv[2][OT];
  __shared__ int sflag;
  int tid = threadIdx.x;           // 192
  int d = tid;
  detect_bf16(xh, tid, &sflag);
  int l0 = blockIdx.x * OT;        // 512 blocks
  float dsum = Ds[d] + Ds[DI+d] + Ds[2*DI+d] + Ds[3*DI+d];
  #pragma unroll
  for (int r=0;r<OT;r++){
    size_t ld = (size_t)(l0+r)*DI + d;
    float y = ydir[ld]
            + ydir[(size_t)LL*DI   + ld]
            + ydir[(size_t)2*LL*DI + ld]
            + ydir[(size_t)3*LL*DI + ld];
    gs[r*WS + d] = fmaf(xc[ld], dsum, y);
  }
  __syncthreads();
  {
    int r = tid / 24, lane = tid - r*24;
    float s1 = 0.f, s2 = 0.f;
    #pragma unroll
    for (int j = lane; j < DI; j += 24){
      float v = gs[r*WS + j];
      s1 += v; s2 += v*v;
    }
    ps[0][r][lane] = s1; ps[1][r][lane] = s2;
  }
  __syncthreads();
  if (tid < OT){
    float a = 0.f, bb = 0.f;
    #pragma unroll
    for (int j=0;j<24;j++){ a += ps[0][tid][j]; bb += ps[1][tid][j]; }
    float mu = a * (1.f/192.f);
    float var = bb * (1.f/192.f) - mu*mu;
    mv[0][tid] = mu; mv[1][tid] = rsqrtf(var + 1e-5f);
  }
  __syncthreads();
  float lg = ln_g[d], lb = ln_b[d];
  #pragma unroll
  for (int r=0;r<OT;r++){
    float yn = (gs[r*WS + d] - mv[0][r]) * mv[1][r] * lg + lb;
    float zv = z[(size_t)(l0+r)*DI + d];
    gs[r*WS + d] = yn * (zv / (1.f + __expf(-zv)));
  }
  __syncthreads();
  int half = tid / 96;
  int e = tid - half*96;
  int r0 = half*4;
  float acc[4];
  #pragma unroll
  for (int i=0;i<4;i++) acc[i] = 0.f;
  const float4* wrow = (const float4*)(opw + e*DI);
  #pragma unroll 4
  for (int jc = 0; jc < DI/4; jc++){
    float4 w = wrow[jc];
    #pragma unroll
    for (int i=0;i<4;i++){
      float4 gv = *(const float4*)&gs[(r0+i)*WS + jc*4];
      acc[i] = fmaf(w.x,gv.x,fmaf(w.y,gv.y,fmaf(w.z,gv.z,fmaf(w.w,gv.w,acc[i]))));
    }
  }
  int f = sflag;
  #pragma unroll
  for (int i=0;i<4;i++){
    int l = l0 + r0 + i;
    if (f) ((__hip_bfloat16*)out)[l*DM + e] = __float2bfloat16(acc[i]);
    else   ((float*)out)[l*DM + e] = acc[i];
  }
}

extern "C" void kernel_launch(void* const* d_in, const int* in_sizes, int n_in,
                              void* d_out, int out_size, void* d_ws, size_t ws_size,
                              hipStream_t stream) {
  float* ws = (float*)d_ws;
  float* cvt = ws + 16;
  const int off[12] = {0,36864,38592,38784,67968,72576,73344,85632,86400,86592,86784,105216};
  float* c[12];
  c[0] = nullptr;
  for (int i = 1; i < 12; i++) c[i] = cvt + off[i-1];

  float* xx   = cvt + 105216;                // LL*DI
  float* z    = xx + (size_t)LL*DI;
  float* xc   = z  + (size_t)LL*DI;
  float* cumD = xc + (size_t)LL*DI;          // CHN*NCH
  float* Harr = cumD + (size_t)CHN*NCH;      // CHN*NC (6.3 MB)
  float* ydir = Harr + (size_t)CHN*NC;       // KD*LL*DI (12.6 MB)
  // total ~29 MB << 256 MiB workspace

  P12 ptrs;
  for (int i = 0; i < 12; i++) ptrs.p[i] = d_in[i];

  k_inprojcvt<<<LL/8 + 178, 384, 0, stream>>>(ptrs, cvt, xx, z);
  k_conv<<<LL, DI, 0, stream>>>(xx, c[2], c[3], xc);
  k_projscan<0><<<KD*CHN, 384, 0, stream>>>(xc, c[4], c[7], c[5], c[6],
                                            cumD, Harr, nullptr);
  k_scan2<CHB><<<NCH/4, 512, 0, stream>>>(c[7], cumD, Harr);
  k_projscan<1><<<KD*CHN, 384, 0, stream>>>(xc, c[4], c[7], c[5], c[6],
                                            cumD, Harr, ydir);
  k_out<<<LL/OT, 192, 0, stream>>>(ydir, xc, z, c[8], c[9], c[10], c[11], d_out,
                                   (const unsigned short*)d_in[0]);
}

// Round 8
// 221.955 us; speedup vs baseline: 1.1662x; 1.1662x over previous
//
#include <hip/hip_runtime.h>
#include <hip/hip_bf16.h>

#define LL 4096
#define DM 96
#define DI 192
#define NS 16
#define RK 6
#define RKP 8              // padded stride for dt coeffs (16B alignment)
#define KD 4
#define CPROJ 38
#define NCH (KD*DI)        // 768 (k,d) pairs
#define NC (KD*DI*NS)      // 12288 independent chains
#define PT 32              // t-tile for proj == scan chunk (CHB=7)
#define WS 196             // LDS row stride (4*odd -> quad-bank spread)
#define OT 8               // l-tile for k_out
#define CHB 7
#define CHN (1<<CHB)       // 128 chunks
#define CS (LL>>CHB)       // 32 steps per chunk == PT
#define L2E 1.44269504f

__device__ __forceinline__ float bf2f(unsigned short u){
  unsigned int x = ((unsigned int)u) << 16;
  return __uint_as_float(x);
}
__device__ __forceinline__ float b2f(__hip_bfloat16 v){ return __bfloat162float(v); }

// inline dtype detect: 64 lanes sample even halfwords of x
__device__ __forceinline__ void detect_bf16(const unsigned short* __restrict__ xh, int tid, int* sflag){
  if (tid < 64){
    unsigned short u = xh[2*tid];
    int e = (u >> 7) & 0xFF;
    int sane = (e >= 107 && e <= 131) ? 1 : 0;
    unsigned long long m = __ballot(sane);
    if (tid == 0) *sflag = (__popcll(m) >= 32) ? 1 : 0;
  }
}

__device__ __forceinline__ int dir_map(int k, int t){
  if (k==0) return t;
  if (k==1) return ((t&63)<<6) | (t>>6);
  if (k==2) return 4095 - t;
  int u = 4095 - t; return ((u&63)<<6) | (u>>6);
}

struct P12 { const void* p[12]; };

// -------- K1: merged {in_proj GEMM (raw w, raw x)} + {param convert 2..11} --------
__global__ void __launch_bounds__(384) k_inprojcvt(P12 ptrs, float* __restrict__ cvt,
                         float* __restrict__ xx, float* __restrict__ z) {
  __shared__ float xr[8*DM];
  __shared__ int sflag;
  int tid = threadIdx.x; // 384
  detect_bf16((const unsigned short*)ptrs.p[0], tid, &sflag);
  __syncthreads();
  int f = sflag;
  if (blockIdx.x >= LL/8){
    const int off[12] = {0,36864,38592,38784,67968,72576,73344,85632,86400,86592,86784,105216};
    int i = (blockIdx.x - LL/8)*384 + tid + 36864;
    if (i < 105216){
      int j = 1;
      #pragma unroll
      for (int s = 2; s < 11; s++) if (i >= off[s]) j = s;
      int e = i - off[j];
      const void* src = ptrs.p[j+1];
      cvt[i] = f ? b2f(((const __hip_bfloat16*)src)[e]) : ((const float*)src)[e];
    }
    return;
  }
  int l0 = blockIdx.x * 8;
  if (f){
    const __hip_bfloat16* xb = (const __hip_bfloat16*)ptrs.p[0] + (size_t)l0*DM;
    for (int i = tid; i < 8*DM; i += 384) xr[i] = b2f(xb[i]);
  } else {
    const float* xf = (const float*)ptrs.p[0] + (size_t)l0*DM;
    for (int i = tid; i < 8*DM; i += 384) xr[i] = xf[i];
  }
  __syncthreads();
  int e = tid;
  float acc[8];
  #pragma unroll
  for (int i=0;i<8;i++) acc[i]=0.f;
  const float4* xr4 = (const float4*)xr;   // rows of 24 float4
  if (f){
    const ushort4* wb = (const ushort4*)((const unsigned short*)ptrs.p[1] + (size_t)e*DM);
    #pragma unroll 4
    for (int c4=0;c4<DM/4;c4++){
      ushort4 uv = wb[c4];
      float4 wv = make_float4(bf2f(uv.x), bf2f(uv.y), bf2f(uv.z), bf2f(uv.w));
      #pragma unroll
      for (int i=0;i<8;i++){
        float4 xv = xr4[i*24 + c4];
        acc[i] = fmaf(wv.x,xv.x,fmaf(wv.y,xv.y,fmaf(wv.z,xv.z,fmaf(wv.w,xv.w,acc[i]))));
      }
    }
  } else {
    const float4* wr4 = (const float4*)((const float*)ptrs.p[1] + (size_t)e*DM);
    #pragma unroll 4
    for (int c4=0;c4<DM/4;c4++){
      float4 wv = wr4[c4];
      #pragma unroll
      for (int i=0;i<8;i++){
        float4 xv = xr4[i*24 + c4];
        acc[i] = fmaf(wv.x,xv.x,fmaf(wv.y,xv.y,fmaf(wv.z,xv.z,fmaf(wv.w,xv.w,acc[i]))));
      }
    }
  }
  if (e < DI) {
    #pragma unroll
    for (int i=0;i<8;i++) xx[(l0+i)*DI + e] = acc[i];
  } else {
    int e2 = e - DI;
    #pragma unroll
    for (int i=0;i<8;i++) z[(l0+i)*DI + e2] = acc[i];
  }
}

// -------- K2: depthwise 3x3 conv + bias + SiLU --------
__global__ void k_conv(const float* __restrict__ xx,
                       const float* __restrict__ cw,
                       const float* __restrict__ cb,
                       float* __restrict__ xc) {
  int l = blockIdx.x;
  int d = threadIdx.x; // 192
  int h = l >> 6, w = l & 63;
  float acc = cb[d];
  #pragma unroll
  for (int ki=0; ki<3; ki++){
    int hh = h + ki - 1;
    if ((unsigned)hh >= 64u) continue;
    #pragma unroll
    for (int kj=0;kj<3;kj++){
      int wj = w + kj - 1;
      if ((unsigned)wj >= 64u) continue;
      acc = fmaf(cw[d*9 + ki*3 + kj], xx[(hh*64+wj)*DI + d], acc);
    }
  }
  xc[l*DI + d] = acc / (1.f + __expf(-acc));
}

// -------- K3/K5: fused {proj -> LDS} + {scan}, 384 threads, half-split chains.
// Scan: thread=(d=tid%192, half=tid/192); each half owns 8 n-chains as EXPLICIT
// SCALARS (h0..h7) -- no register arrays, nothing lives across barriers except h.
// MODE 0: summaries; no in-loop barriers; C-rows of proj skipped.
// MODE 1: per-step cross-half reduce through a 2-slot LDS ping-pong (ybuf);
//         half1 writes its partial, one barrier, half0 adds + stores ydir. --------
template<int MODE>
__global__ void __launch_bounds__(384) k_projscan(
                      const float* __restrict__ xc,
                      const float* __restrict__ xpw,
                      const float* __restrict__ A_logs,
                      const float* __restrict__ dtw,
                      const float* __restrict__ dtb,
                      float* __restrict__ cumDbuf,
                      float* __restrict__ Harr,
                      float* __restrict__ ydir) {
  __shared__ float wl[CPROJ*WS];   // 29.8 KB
  __shared__ float xs[PT*WS];      // 25.1 KB
  __shared__ float ds_[PT*RKP];    // 1 KB
  __shared__ float Bs[PT*NS];      // 2 KB
  __shared__ float Cs[PT*NS];      // 2 KB
  __shared__ float ybuf[2*WS];     // 1.5 KB ping-pong (total ~61.5 KB -> 2 blk/CU)
  int b = blockIdx.x;              // KD * 128
  int k = b >> 7;
  int c = b & 127;
  int t_base = c * PT;             // == t0 of chunk c (CS == PT)
  int tid = threadIdx.x;           // 384

  // ---- proj staging ----
  for (int idx = tid; idx < CPROJ*DI; idx += 384){
    int cc = idx / DI, j = idx - cc*DI;
    wl[cc*WS + j] = xpw[(k*CPROJ + cc)*DI + j];
  }
  for (int idx = tid; idx < PT*DI; idx += 384){
    int tt = idx / DI, j = idx - tt*DI;
    xs[tt*WS + j] = xc[(size_t)dir_map(k, t_base + tt)*DI + j];
  }
  __syncthreads();

  // ---- proj compute -> LDS ds_/Bs/Cs (256 threads; MODE0 skips C rows) ----
  if (tid < 256){
    int tg = tid & 7;        // t cols {tg, tg+8, tg+16, tg+24}
    int ty = tid >> 3;       // rows {ty, ty+32 if <38}
    int cc0 = ty;
    int need0 = (MODE == 0) ? (cc0 < RK+NS) : 1;       // MODE0: skip C rows
    int has2 = (MODE == 0) ? 0 : (ty + 32 < CPROJ);    // rows 32..37 are all C
    int cc1 = has2 ? (ty + 32) : ty;
    float a0x=0.f,a0y=0.f,a0z=0.f,a0w=0.f;
    float a1x=0.f,a1y=0.f,a1z=0.f,a1w=0.f;
    const float4* w0p = (const float4*)&wl[cc0*WS];
    const float4* w1p = (const float4*)&wl[cc1*WS];
    const float4* x0p = (const float4*)&xs[(tg     )*WS];
    const float4* x1p = (const float4*)&xs[(tg +  8)*WS];
    const float4* x2p = (const float4*)&xs[(tg + 16)*WS];
    const float4* x3p = (const float4*)&xs[(tg + 24)*WS];
    if (need0){
      #pragma unroll 4
      for (int jc = 0; jc < DI/4; jc++){
        float4 w0 = w0p[jc], w1 = w1p[jc];
        float4 x0 = x0p[jc], x1 = x1p[jc], x2 = x2p[jc], x3 = x3p[jc];
        a0x = fmaf(w0.x,x0.x,fmaf(w0.y,x0.y,fmaf(w0.z,x0.z,fmaf(w0.w,x0.w,a0x))));
        a0y = fmaf(w0.x,x1.x,fmaf(w0.y,x1.y,fmaf(w0.z,x1.z,fmaf(w0.w,x1.w,a0y))));
        a0z = fmaf(w0.x,x2.x,fmaf(w0.y,x2.y,fmaf(w0.z,x2.z,fmaf(w0.w,x2.w,a0z))));
        a0w = fmaf(w0.x,x3.x,fmaf(w0.y,x3.y,fmaf(w0.z,x3.z,fmaf(w0.w,x3.w,a0w))));
        if (has2){
          a1x = fmaf(w1.x,x0.x,fmaf(w1.y,x0.y,fmaf(w1.z,x0.z,fmaf(w1.w,x0.w,a1x))));
          a1y = fmaf(w1.x,x1.x,fmaf(w1.y,x1.y,fmaf(w1.z,x1.z,fmaf(w1.w,x1.w,a1y))));
          a1z = fmaf(w1.x,x2.x,fmaf(w1.y,x2.y,fmaf(w1.z,x2.z,fmaf(w1.w,x2.w,a1z))));
          a1w = fmaf(w1.x,x3.x,fmaf(w1.y,x3.y,fmaf(w1.z,x3.z,fmaf(w1.w,x3.w,a1w))));
        }
      }
    }
    float accs0[4] = {a0x,a0y,a0z,a0w};
    float accs1[4] = {a1x,a1y,a1z,a1w};
    #pragma unroll
    for (int i=0;i<4;i++){
      int t = tg + 8*i;            // LOCAL chunk index 0..31
      if (need0){
        int cc = cc0; float v = accs0[i];
        if (cc < RK)            ds_[t*RKP + cc] = v;
        else if (cc < RK+NS)    Bs [t*NS + (cc-RK)] = v;
        else                    Cs [t*NS + (cc-RK-NS)] = v;
      }
      if (has2){
        int cc = cc1; float v = accs1[i];
        if (cc < RK+NS)         Bs [t*NS + (cc-RK)] = v;
        else                    Cs [t*NS + (cc-RK-NS)] = v;
      }
    }
  }
  __syncthreads();

  // ---- scan over the LDS-resident chunk: all 384 threads, explicit scalars ----
  {
    int half = (tid >= DI) ? 1 : 0;      // wave-aligned (192 = 3 waves)
    int d = tid - half*DI;
    int kd = k*DI + d;
    int n0 = half*8;
    float bt = dtb[kd];
    float w0 = dtw[kd*RK+0], w1 = dtw[kd*RK+1], w2 = dtw[kd*RK+2];
    float w3 = dtw[kd*RK+3], w4 = dtw[kd*RK+4], w5 = dtw[kd*RK+5];
    float a0,a1,a2,a3,a4,a5,a6,a7;
    {
      const float4* ap = (const float4*)&A_logs[kd*NS] + half*2;
      float4 av0 = ap[0], av1 = ap[1];
      a0 = -__expf(av0.x)*L2E; a1 = -__expf(av0.y)*L2E;
      a2 = -__expf(av0.z)*L2E; a3 = -__expf(av0.w)*L2E;
      a4 = -__expf(av1.x)*L2E; a5 = -__expf(av1.y)*L2E;
      a6 = -__expf(av1.z)*L2E; a7 = -__expf(av1.w)*L2E;
    }
    float h0,h1,h2,h3,h4,h5,h6,h7;
    if (MODE == 0){
      h0=h1=h2=h3=h4=h5=h6=h7=0.f;
    } else {
      const float4* hp = (const float4*)(Harr + ((size_t)c*NCH + kd)*16) + half*2;
      float4 hv0 = hp[0], hv1 = hp[1];
      h0=hv0.x; h1=hv0.y; h2=hv0.z; h3=hv0.w;
      h4=hv1.x; h5=hv1.y; h6=hv1.z; h7=hv1.w;
    }
    float cumD = 0.f;
    #pragma unroll 2
    for (int s=0; s<CS; s++){
      float4 lo = *(const float4*)(ds_ + s*RKP);
      float4 hi = *(const float4*)(ds_ + s*RKP + 4);
      float v = bt;
      v = fmaf(w0, lo.x, v); v = fmaf(w1, lo.y, v); v = fmaf(w2, lo.z, v);
      v = fmaf(w3, lo.w, v); v = fmaf(w4, hi.x, v); v = fmaf(w5, hi.y, v);
      float sp = (v > 20.f) ? v : __logf(1.f + __expf(v));
      if (MODE == 0) cumD += sp;
      float sx = sp * xs[s*WS + d];
      float4 b0 = *(const float4*)(Bs + s*NS + n0);
      float4 b1 = *(const float4*)(Bs + s*NS + n0 + 4);
      float e;
      e = exp2f(sp*a0); h0 = fmaf(e, h0, sx*b0.x);
      e = exp2f(sp*a1); h1 = fmaf(e, h1, sx*b0.y);
      e = exp2f(sp*a2); h2 = fmaf(e, h2, sx*b0.z);
      e = exp2f(sp*a3); h3 = fmaf(e, h3, sx*b0.w);
      e = exp2f(sp*a4); h4 = fmaf(e, h4, sx*b1.x);
      e = exp2f(sp*a5); h5 = fmaf(e, h5, sx*b1.y);
      e = exp2f(sp*a6); h6 = fmaf(e, h6, sx*b1.z);
      e = exp2f(sp*a7); h7 = fmaf(e, h7, sx*b1.w);
      if (MODE == 1){
        float4 c0 = *(const float4*)(Cs + s*NS + n0);
        float4 c1 = *(const float4*)(Cs + s*NS + n0 + 4);
        float m0 = fmaf(h1, c0.y, h0*c0.x);
        float m1 = fmaf(h3, c0.w, h2*c0.z);
        float m2 = fmaf(h5, c1.y, h4*c1.x);
        float m3 = fmaf(h7, c1.w, h6*c1.z);
        float p = (m0+m1)+(m2+m3);
        if (half == 1) ybuf[(s&1)*WS + d] = p;
        __syncthreads();
        if (half == 0){
          int row = dir_map(k, t_base + s);
          ydir[((size_t)k*LL + row)*DI + d] = p + ybuf[(s&1)*WS + d];
        }
      }
    }
    if (MODE == 0){
      if (half == 0) cumDbuf[(size_t)c*NCH + kd] = cumD;
      float4* hp = (float4*)(Harr + ((size_t)c*NCH + kd)*16) + half*2;
      hp[0] = make_float4(h0,h1,h2,h3);
      hp[1] = make_float4(h4,h5,h6,h7);
    }
  }
}

// -------- K4: cross-chunk combine, LDS-staged (CHB=7) --------
template<int CB>
__global__ void __launch_bounds__(512) k_scan2(const float* __restrict__ A_logs,
                                               const float* __restrict__ cumDbuf,
                                               float* __restrict__ Harr) {
  constexpr int CH = 1 << CB;
  constexpr int CHP = CH + 1;      // +1 pad
  __shared__ float hs[64][CHP];    // 33 KB @CB=7
  __shared__ float cds[4][CH];
  int tid = threadIdx.x;           // 512
  int base = blockIdx.x * 64;      // chain base
  int kd0 = blockIdx.x * 4;
  for (int i4 = tid; i4 < 16*CH; i4 += 512){
    int c = i4 >> 4;
    int jv = (i4 & 15) * 4;
    float4 v = *(const float4*)&Harr[(size_t)c*NC + base + jv];
    hs[jv][c] = v.x; hs[jv+1][c] = v.y; hs[jv+2][c] = v.z; hs[jv+3][c] = v.w;
  }
  for (int i = tid; i < 4*CH; i += 512){
    int c = i >> 2, kdl = i & 3;
    cds[kdl][c] = cumDbuf[(size_t)c*NCH + kd0 + kdl];
  }
  __syncthreads();
  if (tid < 64){
    float A2 = -__expf(A_logs[base + tid]) * L2E;
    const float* cd = cds[tid >> 4];
    float* hr = hs[tid];
    float h = 0.f;
    #pragma unroll 4
    for (int c = 0; c < CH; c++){
      float hl = hr[c];
      float P = exp2f(A2 * cd[c]);
      hr[c] = h;                   // entry state
      h = fmaf(P, h, hl);
    }
  }
  __syncthreads();
  for (int i4 = tid; i4 < 16*CH; i4 += 512){
    int c = i4 >> 4;
    int jv = (i4 & 15) * 4;
    float4 v = make_float4(hs[jv][c], hs[jv+1][c], hs[jv+2][c], hs[jv+3][c]);
    *(float4*)&Harr[(size_t)c*NC + base + jv] = v;
  }
}

// -------- K6: fused gather + LayerNorm + gate + out_proj --------
__global__ void __launch_bounds__(192) k_out(
                      const float* __restrict__ ydir,
                      const float* __restrict__ xc,
                      const float* __restrict__ z,
                      const float* __restrict__ Ds,
                      const float* __restrict__ ln_g,
                      const float* __restrict__ ln_b,
                      const float* __restrict__ opw,
                      void* __restrict__ out,
                      const unsigned short* __restrict__ xh) {
  __shared__ float gs[OT*WS];      // 6.3 KB
  __shared__ float ps[2][OT][24];
  __shared__ float mv[2][OT];
  __shared__ int sflag;
  int tid = threadIdx.x;           // 192
  int d = tid;
  detect_bf16(xh, tid, &sflag);
  int l0 = blockIdx.x * OT;        // 512 blocks
  float dsum = Ds[d] + Ds[DI+d] + Ds[2*DI+d] + Ds[3*DI+d];
  #pragma unroll
  for (int r=0;r<OT;r++){
    size_t ld = (size_t)(l0+r)*DI + d;
    float y = ydir[ld]
            + ydir[(size_t)LL*DI   + ld]
            + ydir[(size_t)2*LL*DI + ld]
            + ydir[(size_t)3*LL*DI + ld];
    gs[r*WS + d] = fmaf(xc[ld], dsum, y);
  }
  __syncthreads();
  {
    int r = tid / 24, lane = tid - r*24;
    float s1 = 0.f, s2 = 0.f;
    #pragma unroll
    for (int j = lane; j < DI; j += 24){
      float v = gs[r*WS + j];
      s1 += v; s2 += v*v;
    }
    ps[0][r][lane] = s1; ps[1][r][lane] = s2;
  }
  __syncthreads();
  if (tid < OT){
    float a = 0.f, bb = 0.f;
    #pragma unroll
    for (int j=0;j<24;j++){ a += ps[0][tid][j]; bb += ps[1][tid][j]; }
    float mu = a * (1.f/192.f);
    float var = bb * (1.f/192.f) - mu*mu;
    mv[0][tid] = mu; mv[1][tid] = rsqrtf(var + 1e-5f);
  }
  __syncthreads();
  float lg = ln_g[d], lb = ln_b[d];
  #pragma unroll
  for (int r=0;r<OT;r++){
    float yn = (gs[r*WS + d] - mv[0][r]) * mv[1][r] * lg + lb;
    float zv = z[(size_t)(l0+r)*DI + d];
    gs[r*WS + d] = yn * (zv / (1.f + __expf(-zv)));
  }
  __syncthreads();
  int half = tid / 96;
  int e = tid - half*96;
  int r0 = half*4;
  float acc[4];
  #pragma unroll
  for (int i=0;i<4;i++) acc[i] = 0.f;
  const float4* wrow = (const float4*)(opw + e*DI);
  #pragma unroll 4
  for (int jc = 0; jc < DI/4; jc++){
    float4 w = wrow[jc];
    #pragma unroll
    for (int i=0;i<4;i++){
      float4 gv = *(const float4*)&gs[(r0+i)*WS + jc*4];
      acc[i] = fmaf(w.x,gv.x,fmaf(w.y,gv.y,fmaf(w.z,gv.z,fmaf(w.w,gv.w,acc[i]))));
    }
  }
  int f = sflag;
  #pragma unroll
  for (int i=0;i<4;i++){
    int l = l0 + r0 + i;
    if (f) ((__hip_bfloat16*)out)[l*DM + e] = __float2bfloat16(acc[i]);
    else   ((float*)out)[l*DM + e] = acc[i];
  }
}

extern "C" void kernel_launch(void* const* d_in, const int* in_sizes, int n_in,
                              void* d_out, int out_size, void* d_ws, size_t ws_size,
                              hipStream_t stream) {
  float* ws = (float*)d_ws;
  float* cvt = ws + 16;
  const int off[12] = {0,36864,38592,38784,67968,72576,73344,85632,86400,86592,86784,105216};
  float* c[12];
  c[0] = nullptr;
  for (int i = 1; i < 12; i++) c[i] = cvt + off[i-1];

  float* xx   = cvt + 105216;                // LL*DI
  float* z    = xx + (size_t)LL*DI;
  float* xc   = z  + (size_t)LL*DI;
  float* cumD = xc + (size_t)LL*DI;          // CHN*NCH
  float* Harr = cumD + (size_t)CHN*NCH;      // CHN*NC (6.3 MB)
  float* ydir = Harr + (size_t)CHN*NC;       // KD*LL*DI (12.6 MB)
  // total ~29 MB << 256 MiB workspace

  P12 ptrs;
  for (int i = 0; i < 12; i++) ptrs.p[i] = d_in[i];

  k_inprojcvt<<<LL/8 + 178, 384, 0, stream>>>(ptrs, cvt, xx, z);
  k_conv<<<LL, DI, 0, stream>>>(xx, c[2], c[3], xc);
  k_projscan<0><<<KD*CHN, 384, 0, stream>>>(xc, c[4], c[7], c[5], c[6],
                                            cumD, Harr, nullptr);
  k_scan2<CHB><<<NCH/4, 512, 0, stream>>>(c[7], cumD, Harr);
  k_projscan<1><<<KD*CHN, 384, 0, stream>>>(xc, c[4], c[7], c[5], c[6],
                                            cumD, Harr, ydir);
  k_out<<<LL/OT, 192, 0, stream>>>(ydir, xc, z, c[8], c[9], c[10], c[11], d_out,
                                   (const unsigned short*)d_in[0]);
}

// Round 9
// 198.787 us; speedup vs baseline: 1.3021x; 1.1165x over previous
//
#include <hip/hip_runtime.h>
#include <hip/hip_bf16.h>

#define LL 4096
#define DM 96
#define DI 192
#define NS 16
#define RK 6
#define RKP 8              // padded stride for dt coeffs (16B alignment)
#define KD 4
#define CPROJ 38
#define NCH (KD*DI)        // 768 (k,d) pairs
#define NC (KD*DI*NS)      // 12288 independent chains
#define PT 32              // t-tile for k_proj
#define WS 196             // LDS row stride (4*odd -> quad-bank spread)
#define OT 8               // l-tile for k_out
#define CHB 8
#define CHN (1<<CHB)       // 256 chunks
#define CS (LL>>CHB)       // 16 steps per chunk
#define L2E 1.44269504f

__device__ __forceinline__ float bf2f(unsigned short u){
  unsigned int x = ((unsigned int)u) << 16;
  return __uint_as_float(x);
}
__device__ __forceinline__ float b2f(__hip_bfloat16 v){ return __bfloat162float(v); }

// inline dtype detect: 64 lanes sample even halfwords of x
__device__ __forceinline__ void detect_bf16(const unsigned short* __restrict__ xh, int tid, int* sflag){
  if (tid < 64){
    unsigned short u = xh[2*tid];
    int e = (u >> 7) & 0xFF;
    int sane = (e >= 107 && e <= 131) ? 1 : 0;
    unsigned long long m = __ballot(sane);
    if (tid == 0) *sflag = (__popcll(m) >= 32) ? 1 : 0;
  }
}

__device__ __forceinline__ int dir_map(int k, int t){
  if (k==0) return t;
  if (k==1) return ((t&63)<<6) | (t>>6);
  if (k==2) return 4095 - t;
  int u = 4095 - t; return ((u&63)<<6) | (u>>6);
}

struct P12 { const void* p[12]; };

// -------- K1: merged {in_proj GEMM (raw w, raw x)} + {param convert 2..11} --------
__global__ void __launch_bounds__(384) k_inprojcvt(P12 ptrs, float* __restrict__ cvt,
                         float* __restrict__ xx, float* __restrict__ z) {
  __shared__ float xr[8*DM];
  __shared__ int sflag;
  int tid = threadIdx.x; // 384
  detect_bf16((const unsigned short*)ptrs.p[0], tid, &sflag);
  __syncthreads();
  int f = sflag;
  if (blockIdx.x >= LL/8){
    const int off[12] = {0,36864,38592,38784,67968,72576,73344,85632,86400,86592,86784,105216};
    int i = (blockIdx.x - LL/8)*384 + tid + 36864;
    if (i < 105216){
      int j = 1;
      #pragma unroll
      for (int s = 2; s < 11; s++) if (i >= off[s]) j = s;
      int e = i - off[j];
      const void* src = ptrs.p[j+1];
      cvt[i] = f ? b2f(((const __hip_bfloat16*)src)[e]) : ((const float*)src)[e];
    }
    return;
  }
  int l0 = blockIdx.x * 8;
  if (f){
    const __hip_bfloat16* xb = (const __hip_bfloat16*)ptrs.p[0] + (size_t)l0*DM;
    for (int i = tid; i < 8*DM; i += 384) xr[i] = b2f(xb[i]);
  } else {
    const float* xf = (const float*)ptrs.p[0] + (size_t)l0*DM;
    for (int i = tid; i < 8*DM; i += 384) xr[i] = xf[i];
  }
  __syncthreads();
  int e = tid;
  float acc[8];
  #pragma unroll
  for (int i=0;i<8;i++) acc[i]=0.f;
  const float4* xr4 = (const float4*)xr;   // rows of 24 float4
  if (f){
    const ushort4* wb = (const ushort4*)((const unsigned short*)ptrs.p[1] + (size_t)e*DM);
    #pragma unroll 4
    for (int c4=0;c4<DM/4;c4++){
      ushort4 uv = wb[c4];
      float4 wv = make_float4(bf2f(uv.x), bf2f(uv.y), bf2f(uv.z), bf2f(uv.w));
      #pragma unroll
      for (int i=0;i<8;i++){
        float4 xv = xr4[i*24 + c4];
        acc[i] = fmaf(wv.x,xv.x,fmaf(wv.y,xv.y,fmaf(wv.z,xv.z,fmaf(wv.w,xv.w,acc[i]))));
      }
    }
  } else {
    const float4* wr4 = (const float4*)((const float*)ptrs.p[1] + (size_t)e*DM);
    #pragma unroll 4
    for (int c4=0;c4<DM/4;c4++){
      float4 wv = wr4[c4];
      #pragma unroll
      for (int i=0;i<8;i++){
        float4 xv = xr4[i*24 + c4];
        acc[i] = fmaf(wv.x,xv.x,fmaf(wv.y,xv.y,fmaf(wv.z,xv.z,fmaf(wv.w,xv.w,acc[i]))));
      }
    }
  }
  if (e < DI) {
    #pragma unroll
    for (int i=0;i<8;i++) xx[(l0+i)*DI + e] = acc[i];
  } else {
    int e2 = e - DI;
    #pragma unroll
    for (int i=0;i<8;i++) z[(l0+i)*DI + e2] = acc[i];
  }
}

// -------- K2: depthwise 3x3 conv + bias + SiLU --------
__global__ void k_conv(const float* __restrict__ xx,
                       const float* __restrict__ cw,
                       const float* __restrict__ cb,
                       float* __restrict__ xc) {
  int l = blockIdx.x;
  int d = threadIdx.x; // 192
  int h = l >> 6, w = l & 63;
  float acc = cb[d];
  #pragma unroll
  for (int ki=0; ki<3; ki++){
    int hh = h + ki - 1;
    if ((unsigned)hh >= 64u) continue;
    #pragma unroll
    for (int kj=0;kj<3;kj++){
      int wj = w + kj - 1;
      if ((unsigned)wj >= 64u) continue;
      acc = fmaf(cw[d*9 + ki*3 + kj], xx[(hh*64+wj)*DI + d], acc);
    }
  }
  xc[l*DI + d] = acc / (1.f + __expf(-acc));
}

// -------- K3: x_dbl projection as register-tiled LDS GEMM (global outputs) --------
__global__ void __launch_bounds__(256) k_proj(const float* __restrict__ xc,
                       const float* __restrict__ xpw,
                       float* __restrict__ dts,
                       float* __restrict__ Bb, float* __restrict__ Cb) {
  __shared__ float wl[CPROJ*WS];   // 29.8 KB
  __shared__ float xs[PT*WS];      // 25.1 KB
  int b = blockIdx.x;              // KD * 128
  int k = b >> 7;
  int t_base = (b & 127) * PT;
  int tid = threadIdx.x;
  for (int idx = tid; idx < CPROJ*DI; idx += 256){
    int cc = idx / DI, j = idx - cc*DI;
    wl[cc*WS + j] = xpw[(k*CPROJ + cc)*DI + j];
  }
  for (int idx = tid; idx < PT*DI; idx += 256){
    int tt = idx / DI, j = idx - tt*DI;
    xs[tt*WS + j] = xc[(size_t)dir_map(k, t_base + tt)*DI + j];
  }
  __syncthreads();
  int tg = tid & 7;
  int ty = tid >> 3;
  int cc0 = ty;
  int has2 = (ty + 32 < CPROJ);
  int cc1 = has2 ? (ty + 32) : ty;
  float a0x=0.f,a0y=0.f,a0z=0.f,a0w=0.f;
  float a1x=0.f,a1y=0.f,a1z=0.f,a1w=0.f;
  const float4* w0p = (const float4*)&wl[cc0*WS];
  const float4* w1p = (const float4*)&wl[cc1*WS];
  const float4* x0p = (const float4*)&xs[(tg     )*WS];
  const float4* x1p = (const float4*)&xs[(tg +  8)*WS];
  const float4* x2p = (const float4*)&xs[(tg + 16)*WS];
  const float4* x3p = (const float4*)&xs[(tg + 24)*WS];
  #pragma unroll 4
  for (int jc = 0; jc < DI/4; jc++){
    float4 w0 = w0p[jc], w1 = w1p[jc];
    float4 x0 = x0p[jc], x1 = x1p[jc], x2 = x2p[jc], x3 = x3p[jc];
    a0x = fmaf(w0.x,x0.x,fmaf(w0.y,x0.y,fmaf(w0.z,x0.z,fmaf(w0.w,x0.w,a0x))));
    a0y = fmaf(w0.x,x1.x,fmaf(w0.y,x1.y,fmaf(w0.z,x1.z,fmaf(w0.w,x1.w,a0y))));
    a0z = fmaf(w0.x,x2.x,fmaf(w0.y,x2.y,fmaf(w0.z,x2.z,fmaf(w0.w,x2.w,a0z))));
    a0w = fmaf(w0.x,x3.x,fmaf(w0.y,x3.y,fmaf(w0.z,x3.z,fmaf(w0.w,x3.w,a0w))));
    a1x = fmaf(w1.x,x0.x,fmaf(w1.y,x0.y,fmaf(w1.z,x0.z,fmaf(w1.w,x0.w,a1x))));
    a1y = fmaf(w1.x,x1.x,fmaf(w1.y,x1.y,fmaf(w1.z,x1.z,fmaf(w1.w,x1.w,a1y))));
    a1z = fmaf(w1.x,x2.x,fmaf(w1.y,x2.y,fmaf(w1.z,x2.z,fmaf(w1.w,x2.w,a1z))));
    a1w = fmaf(w1.x,x3.x,fmaf(w1.y,x3.y,fmaf(w1.z,x3.z,fmaf(w1.w,x3.w,a1w))));
  }
  float accs0[4] = {a0x,a0y,a0z,a0w};
  float accs1[4] = {a1x,a1y,a1z,a1w};
  #pragma unroll
  for (int i=0;i<4;i++){
    int t = t_base + tg + 8*i;
    size_t kt = (size_t)k*LL + t;
    {
      int cc = cc0; float v = accs0[i];
      if (cc < RK)            dts[kt*RKP + cc] = v;
      else if (cc < RK+NS)    Bb [kt*NS + (cc-RK)] = v;
      else                    Cb [kt*NS + (cc-RK-NS)] = v;
    }
    if (has2){
      int cc = ty + 32; float v = accs1[i];
      if (cc < RK+NS)         Bb [kt*NS + (cc-RK)] = v;
      else                    Cb [kt*NS + (cc-RK-NS)] = v;
    }
  }
}

// -------- K4a: summaries pass. 64-thread single-wave blocks, 16 chains/thread.
// Grid = KD*CHN*3 (d split in thirds). Tiny LDS (1.5 KB) -> full-grid residency,
// no in-loop barriers, smooth ramp. Bit-identical fma order to R3 (CHB=8). --------
__global__ void __launch_bounds__(64) k_scanA(
                      const float* __restrict__ xc,
                      const float* __restrict__ dts,
                      const float* __restrict__ Bbuf,
                      const float* __restrict__ A_logs,
                      const float* __restrict__ dtw,
                      const float* __restrict__ dtb,
                      float* __restrict__ cumDbuf,
                      float* __restrict__ Harr) {
  __shared__ float ds_[CS*RKP];    // 128 floats
  __shared__ float Bs[CS*NS];      // 256 floats
  int b = blockIdx.x;              // KD*CHN*3
  int third = b % 3;
  int bc = b / 3;
  int k = bc >> CHB;
  int c = bc & (CHN-1);
  int t0 = c*CS;
  int tid = threadIdx.x;           // 64
  int d = third*64 + tid;
  int kd = k*DI + d;
  for (int i = tid; i < CS*RKP; i += 64) ds_[i] = dts[((size_t)k*LL + t0)*RKP + i];
  for (int i = tid; i < CS*NS;  i += 64) Bs[i]  = Bbuf[((size_t)k*LL + t0)*NS + i];
  float bt = dtb[kd];
  float w0 = dtw[kd*RK+0], w1 = dtw[kd*RK+1], w2 = dtw[kd*RK+2];
  float w3 = dtw[kd*RK+3], w4 = dtw[kd*RK+4], w5 = dtw[kd*RK+5];
  float A2[16], h[16];
  {
    const float4* ap = (const float4*)&A_logs[kd*NS];
    #pragma unroll
    for (int i=0;i<4;i++){
      float4 av = ap[i];
      A2[4*i+0] = -__expf(av.x)*L2E; A2[4*i+1] = -__expf(av.y)*L2E;
      A2[4*i+2] = -__expf(av.z)*L2E; A2[4*i+3] = -__expf(av.w)*L2E;
    }
  }
  #pragma unroll
  for (int n=0;n<16;n++) h[n] = 0.f;
  __syncthreads();
  float cumD = 0.f;
  #pragma unroll 2
  for (int s=0; s<CS; s++){
    float4 lo = *(const float4*)(ds_ + s*RKP);
    float4 hi = *(const float4*)(ds_ + s*RKP + 4);
    float v = bt;
    v = fmaf(w0, lo.x, v); v = fmaf(w1, lo.y, v); v = fmaf(w2, lo.z, v);
    v = fmaf(w3, lo.w, v); v = fmaf(w4, hi.x, v); v = fmaf(w5, hi.y, v);
    float sp = (v > 20.f) ? v : __logf(1.f + __expf(v));
    cumD += sp;
    int row = dir_map(k, t0 + s);
    float sx = sp * xc[(size_t)row*DI + d];
    float4 b0 = *(const float4*)(Bs + s*NS);
    float4 b1 = *(const float4*)(Bs + s*NS + 4);
    float4 b2 = *(const float4*)(Bs + s*NS + 8);
    float4 b3 = *(const float4*)(Bs + s*NS + 12);
    float bb[16] = {b0.x,b0.y,b0.z,b0.w, b1.x,b1.y,b1.z,b1.w,
                    b2.x,b2.y,b2.z,b2.w, b3.x,b3.y,b3.z,b3.w};
    #pragma unroll
    for (int n=0;n<16;n++){
      float aa = exp2f(sp*A2[n]);
      h[n] = fmaf(aa, h[n], sx*bb[n]);
    }
  }
  cumDbuf[(size_t)c*NCH + kd] = cumD;
  float4* hp = (float4*)(Harr + ((size_t)c*NCH + kd)*16);
  hp[0] = make_float4(h[0],h[1],h[2],h[3]);
  hp[1] = make_float4(h[4],h[5],h[6],h[7]);
  hp[2] = make_float4(h[8],h[9],h[10],h[11]);
  hp[3] = make_float4(h[12],h[13],h[14],h[15]);
}

// -------- K4b: cross-chunk combine, LDS-staged (R3 CHB=8 version, proven) --------
template<int CB>
__global__ void __launch_bounds__(512) k_scan2(const float* __restrict__ A_logs,
                                               const float* __restrict__ cumDbuf,
                                               float* __restrict__ Harr) {
  constexpr int CH = 1 << CB;
  constexpr int CHP = CH + 1;      // +1 pad: combine column access -> 2-way (free)
  __shared__ float hs[64][CHP];
  __shared__ float cds[4][CH];
  int tid = threadIdx.x;           // 512
  int base = blockIdx.x * 64;      // chain base
  int kd0 = blockIdx.x * 4;
  for (int i4 = tid; i4 < 16*CH; i4 += 512){
    int c = i4 >> 4;
    int jv = (i4 & 15) * 4;
    float4 v = *(const float4*)&Harr[(size_t)c*NC + base + jv];
    hs[jv][c] = v.x; hs[jv+1][c] = v.y; hs[jv+2][c] = v.z; hs[jv+3][c] = v.w;
  }
  for (int i = tid; i < 4*CH; i += 512){
    int c = i >> 2, kdl = i & 3;
    cds[kdl][c] = cumDbuf[(size_t)c*NCH + kd0 + kdl];
  }
  __syncthreads();
  if (tid < 64){
    float A2 = -__expf(A_logs[base + tid]) * L2E;
    const float* cd = cds[tid >> 4];
    float* hr = hs[tid];
    float h = 0.f;
    #pragma unroll 4
    for (int c = 0; c < CH; c++){
      float hl = hr[c];
      float P = exp2f(A2 * cd[c]);
      hr[c] = h;                   // entry state
      h = fmaf(P, h, hl);
    }
  }
  __syncthreads();
  for (int i4 = tid; i4 < 16*CH; i4 += 512){
    int c = i4 >> 4;
    int jv = (i4 & 15) * 4;
    float4 v = make_float4(hs[jv][c], hs[jv+1][c], hs[jv+2][c], hs[jv+3][c]);
    *(float4*)&Harr[(size_t)c*NC + base + jv] = v;
  }
}

// -------- K4c: final pass, 64-thread blocks, seeded entry states; y at spatial idx --------
__global__ void __launch_bounds__(64) k_scanB(
                      const float* __restrict__ xc,
                      const float* __restrict__ dts,
                      const float* __restrict__ Bbuf,
                      const float* __restrict__ Cbuf,
                      const float* __restrict__ A_logs,
                      const float* __restrict__ dtw,
                      const float* __restrict__ dtb,
                      const float* __restrict__ Harr,   // entry states
                      float* __restrict__ ydir) {
  __shared__ float ds_[CS*RKP];    // 128
  __shared__ float Bs[CS*NS];      // 256
  __shared__ float Cs[CS*NS];      // 256
  int b = blockIdx.x;
  int third = b % 3;
  int bc = b / 3;
  int k = bc >> CHB;
  int c = bc & (CHN-1);
  int t0 = c*CS;
  int tid = threadIdx.x;           // 64
  int d = third*64 + tid;
  int kd = k*DI + d;
  for (int i = tid; i < CS*RKP; i += 64) ds_[i] = dts[((size_t)k*LL + t0)*RKP + i];
  for (int i = tid; i < CS*NS;  i += 64) Bs[i]  = Bbuf[((size_t)k*LL + t0)*NS + i];
  for (int i = tid; i < CS*NS;  i += 64) Cs[i]  = Cbuf[((size_t)k*LL + t0)*NS + i];
  float bt = dtb[kd];
  float w0 = dtw[kd*RK+0], w1 = dtw[kd*RK+1], w2 = dtw[kd*RK+2];
  float w3 = dtw[kd*RK+3], w4 = dtw[kd*RK+4], w5 = dtw[kd*RK+5];
  float A2[16], h[16];
  {
    const float4* ap = (const float4*)&A_logs[kd*NS];
    #pragma unroll
    for (int i=0;i<4;i++){
      float4 av = ap[i];
      A2[4*i+0] = -__expf(av.x)*L2E; A2[4*i+1] = -__expf(av.y)*L2E;
      A2[4*i+2] = -__expf(av.z)*L2E; A2[4*i+3] = -__expf(av.w)*L2E;
    }
  }
  {
    const float4* hp = (const float4*)(Harr + ((size_t)c*NCH + kd)*16);
    float4 h0 = hp[0], h1 = hp[1], h2 = hp[2], h3 = hp[3];
    h[0]=h0.x; h[1]=h0.y; h[2]=h0.z; h[3]=h0.w;
    h[4]=h1.x; h[5]=h1.y; h[6]=h1.z; h[7]=h1.w;
    h[8]=h2.x; h[9]=h2.y; h[10]=h2.z; h[11]=h2.w;
    h[12]=h3.x; h[13]=h3.y; h[14]=h3.z; h[15]=h3.w;
  }
  __syncthreads();
  #pragma unroll 2
  for (int s=0; s<CS; s++){
    float4 lo = *(const float4*)(ds_ + s*RKP);
    float4 hi = *(const float4*)(ds_ + s*RKP + 4);
    float v = bt;
    v = fmaf(w0, lo.x, v); v = fmaf(w1, lo.y, v); v = fmaf(w2, lo.z, v);
    v = fmaf(w3, lo.w, v); v = fmaf(w4, hi.x, v); v = fmaf(w5, hi.y, v);
    float sp = (v > 20.f) ? v : __logf(1.f + __expf(v));
    int row = dir_map(k, t0 + s);
    float sx = sp * xc[(size_t)row*DI + d];
    float4 b0 = *(const float4*)(Bs + s*NS);
    float4 b1 = *(const float4*)(Bs + s*NS + 4);
    float4 b2 = *(const float4*)(Bs + s*NS + 8);
    float4 b3 = *(const float4*)(Bs + s*NS + 12);
    float bb[16] = {b0.x,b0.y,b0.z,b0.w, b1.x,b1.y,b1.z,b1.w,
                    b2.x,b2.y,b2.z,b2.w, b3.x,b3.y,b3.z,b3.w};
    #pragma unroll
    for (int n=0;n<16;n++){
      float aa = exp2f(sp*A2[n]);
      h[n] = fmaf(aa, h[n], sx*bb[n]);
    }
    float4 c0 = *(const float4*)(Cs + s*NS);
    float4 c1 = *(const float4*)(Cs + s*NS + 4);
    float4 c2 = *(const float4*)(Cs + s*NS + 8);
    float4 c3 = *(const float4*)(Cs + s*NS + 12);
    float cc[16] = {c0.x,c0.y,c0.z,c0.w, c1.x,c1.y,c1.z,c1.w,
                    c2.x,c2.y,c2.z,c2.w, c3.x,c3.y,c3.z,c3.w};
    float y0=0.f, y1=0.f, y2=0.f, y3=0.f;
    #pragma unroll
    for (int n=0;n<4;n++){
      y0 = fmaf(h[4*n+0], cc[4*n+0], y0);
      y1 = fmaf(h[4*n+1], cc[4*n+1], y1);
      y2 = fmaf(h[4*n+2], cc[4*n+2], y2);
      y3 = fmaf(h[4*n+3], cc[4*n+3], y3);
    }
    ydir[((size_t)k*LL + row)*DI + d] = (y0+y1)+(y2+y3);
  }
}

// -------- K6: fused gather + LayerNorm + gate + out_proj --------
__global__ void __launch_bounds__(192) k_out(
                      const float* __restrict__ ydir,
                      const float* __restrict__ xc,
                      const float* __restrict__ z,
                      const float* __restrict__ Ds,
                      const float* __restrict__ ln_g,
                      const float* __restrict__ ln_b,
                      const float* __restrict__ opw,
                      void* __restrict__ out,
                      const unsigned short* __restrict__ xh) {
  __shared__ float gs[OT*WS];      // 6.3 KB
  __shared__ float ps[2][OT][24];
  __shared__ float mv[2][OT];
  __shared__ int sflag;
  int tid = threadIdx.x;           // 192
  int d = tid;
  detect_bf16(xh, tid, &sflag);
  int l0 = blockIdx.x * OT;        // 512 blocks
  float dsum = Ds[d] + Ds[DI+d] + Ds[2*DI+d] + Ds[3*DI+d];
  #pragma unroll
  for (int r=0;r<OT;r++){
    size_t ld = (size_t)(l0+r)*DI + d;
    float y = ydir[ld]
            + ydir[(size_t)LL*DI   + ld]
            + ydir[(size_t)2*LL*DI + ld]
            + ydir[(size_t)3*LL*DI + ld];
    gs[r*WS + d] = fmaf(xc[ld], dsum, y);
  }
  __syncthreads();
  {
    int r = tid / 24, lane = tid - r*24;
    float s1 = 0.f, s2 = 0.f;
    #pragma unroll
    for (int j = lane; j < DI; j += 24){
      float v = gs[r*WS + j];
      s1 += v; s2 += v*v;
    }
    ps[0][r][lane] = s1; ps[1][r][lane] = s2;
  }
  __syncthreads();
  if (tid < OT){
    float a = 0.f, bb = 0.f;
    #pragma unroll
    for (int j=0;j<24;j++){ a += ps[0][tid][j]; bb += ps[1][tid][j]; }
    float mu = a * (1.f/192.f);
    float var = bb * (1.f/192.f) - mu*mu;
    mv[0][tid] = mu; mv[1][tid] = rsqrtf(var + 1e-5f);
  }
  __syncthreads();
  float lg = ln_g[d], lb = ln_b[d];
  #pragma unroll
  for (int r=0;r<OT;r++){
    float yn = (gs[r*WS + d] - mv[0][r]) * mv[1][r] * lg + lb;
    float zv = z[(size_t)(l0+r)*DI + d];
    gs[r*WS + d] = yn * (zv / (1.f + __expf(-zv)));
  }
  __syncthreads();
  int half = tid / 96;
  int e = tid - half*96;
  int r0 = half*4;
  float acc[4];
  #pragma unroll
  for (int i=0;i<4;i++) acc[i] = 0.f;
  const float4* wrow = (const float4*)(opw + e*DI);
  #pragma unroll 4
  for (int jc = 0; jc < DI/4; jc++){
    float4 w = wrow[jc];
    #pragma unroll
    for (int i=0;i<4;i++){
      float4 gv = *(const float4*)&gs[(r0+i)*WS + jc*4];
      acc[i] = fmaf(w.x,gv.x,fmaf(w.y,gv.y,fmaf(w.z,gv.z,fmaf(w.w,gv.w,acc[i]))));
    }
  }
  int f = sflag;
  #pragma unroll
  for (int i=0;i<4;i++){
    int l = l0 + r0 + i;
    if (f) ((__hip_bfloat16*)out)[l*DM + e] = __float2bfloat16(acc[i]);
    else   ((float*)out)[l*DM + e] = acc[i];
  }
}

extern "C" void kernel_launch(void* const* d_in, const int* in_sizes, int n_in,
                              void* d_out, int out_size, void* d_ws, size_t ws_size,
                              hipStream_t stream) {
  float* ws = (float*)d_ws;
  float* cvt = ws + 16;
  const int off[12] = {0,36864,38592,38784,67968,72576,73344,85632,86400,86592,86784,105216};
  float* c[12];
  c[0] = nullptr;
  for (int i = 1; i < 12; i++) c[i] = cvt + off[i-1];

  float* xx   = cvt + 105216;                // LL*DI
  float* z    = xx + (size_t)LL*DI;
  float* xc   = z  + (size_t)LL*DI;
  float* dts  = xc + (size_t)LL*DI;          // KD*LL*RKP
  float* Bb   = dts + (size_t)KD*LL*RKP;     // KD*LL*NS
  float* Cb   = Bb + (size_t)KD*LL*NS;       // KD*LL*NS
  float* cumD = Cb + (size_t)KD*LL*NS;       // CHN*NCH
  float* Harr = cumD + (size_t)CHN*NCH;      // CHN*NC (12.6 MB)
  float* ydir = Harr + (size_t)CHN*NC;       // KD*LL*DI (12.6 MB)
  // total ~45 MB << 256 MiB workspace

  P12 ptrs;
  for (int i = 0; i < 12; i++) ptrs.p[i] = d_in[i];

  k_inprojcvt<<<LL/8 + 178, 384, 0, stream>>>(ptrs, cvt, xx, z);
  k_conv<<<LL, DI, 0, stream>>>(xx, c[2], c[3], xc);
  k_proj<<<KD*(LL/PT), 256, 0, stream>>>(xc, c[4], dts, Bb, Cb);
  k_scanA<<<KD*CHN*3, 64, 0, stream>>>(xc, dts, Bb, c[7], c[5], c[6], cumD, Harr);
  k_scan2<CHB><<<NCH/4, 512, 0, stream>>>(c[7], cumD, Harr);
  k_scanB<<<KD*CHN*3, 64, 0, stream>>>(xc, dts, Bb, Cb, c[7], c[5], c[6], Harr, ydir);
  k_out<<<LL/OT, 192, 0, stream>>>(ydir, xc, z, c[8], c[9], c[10], c[11], d_out,
                                   (const unsigned short*)d_in[0]);
}